// Round 1
// baseline (70.602 us; speedup 1.0000x reference)
//
#include <hip/hip_runtime.h>

#define N_COLORS 131072
#define M_PAL    128
#define BLOCK    256

__global__ __launch_bounds__(BLOCK) void nearest_color_loss_kernel(
    const float* __restrict__ colors,     // (N,3)
    const float* __restrict__ palette,    // (M,3)
    float* __restrict__ out)              // scalar
{
    // Stage palette into LDS as float4 (pad to 16B so the inner loop is one
    // ds_read_b128; all lanes read the same entry -> broadcast, no conflicts).
    __shared__ float4 pal[M_PAL];
    const int tid = threadIdx.x;
    if (tid < M_PAL) {
        const float* p = palette + 3 * tid;
        pal[tid] = make_float4(p[0], p[1], p[2], 0.0f);
    }
    __syncthreads();

    const int gid = blockIdx.x * BLOCK + tid;
    // Lane i reads bytes [12i, 12i+12) -> contiguous across the wave.
    const float r = colors[3 * gid + 0];
    const float g = colors[3 * gid + 1];
    const float b = colors[3 * gid + 2];

    // min over squared distances; single sqrt at the end (sqrt is monotone).
    float best = 3.0e38f;
#pragma unroll 8
    for (int j = 0; j < M_PAL; ++j) {
        const float4 p = pal[j];
        const float dr = r - p.x;
        const float dg = g - p.y;
        const float db = b - p.z;
        const float d = dr * dr + dg * dg + db * db;
        best = fminf(best, d);
    }
    float v = __builtin_sqrtf(best);

    // Wave-64 shuffle reduction.
#pragma unroll
    for (int off = 32; off > 0; off >>= 1)
        v += __shfl_down(v, off, 64);

    __shared__ float wsum[BLOCK / 64];
    if ((tid & 63) == 0) wsum[tid >> 6] = v;
    __syncthreads();

    if (tid == 0) {
        float s = 0.0f;
#pragma unroll
        for (int w = 0; w < BLOCK / 64; ++w) s += wsum[w];
        atomicAdd(out, s * (1.0f / (float)N_COLORS));
    }
}

extern "C" void kernel_launch(void* const* d_in, const int* in_sizes, int n_in,
                              void* d_out, int out_size, void* d_ws, size_t ws_size,
                              hipStream_t stream) {
    const float* colors  = (const float*)d_in[0];   // (131072, 3) fp32
    const float* palette = (const float*)d_in[1];   // (128, 3) fp32
    float* out = (float*)d_out;                     // 1 fp32 scalar

    // d_out is re-poisoned to 0xAA before every timed launch; zero it.
    // hipMemsetAsync is graph-capture legal (becomes a memset node).
    hipMemsetAsync(out, 0, sizeof(float), stream);

    const int grid = N_COLORS / BLOCK;  // 512 blocks
    nearest_color_loss_kernel<<<grid, BLOCK, 0, stream>>>(colors, palette, out);
}

// Round 2
// 66.444 us; speedup vs baseline: 1.0626x; 1.0626x over previous
//
#include <hip/hip_runtime.h>

#define N_COLORS 131072
#define M_PAL    128
#define BLOCK    256

// Palette (1.5 KB) is read with wave-uniform addresses from a fully unrolled
// loop -> compiler scalarizes to s_load_dwordx4 through the scalar cache.
// This frees both the LDS pipe (old bottleneck: 128 ds_read_b128/wave ~ 5 us
// per CU) and keeps VALU as the only hot pipe (~3584 cyc/SIMD ~ 1.5 us).
__global__ __launch_bounds__(BLOCK) void nearest_color_loss_kernel(
    const float* __restrict__ colors,     // (N,3)
    const float* __restrict__ palette,    // (M,3)
    float* __restrict__ out)              // scalar
{
    const int tid = threadIdx.x;
    const int gid = blockIdx.x * BLOCK + tid;

    // Lane i reads 3 consecutive dwords; wave covers 768 contiguous bytes in
    // 3 coalesced requests. Inputs are L2-resident (1.5 MB) - not a concern.
    const float r = colors[3 * gid + 0];
    const float g = colors[3 * gid + 1];
    const float b = colors[3 * gid + 2];

    // Two independent min-chains (even/odd j): halves the serial fminf
    // dependency (128 -> 64 deep) since we only have 2 waves/SIMD to hide it.
    // min(sqrt(d)) == sqrt(min(d)): one sqrt at the end.
    float best0 = 3.0e38f;
    float best1 = 3.0e38f;
#pragma unroll
    for (int j = 0; j < M_PAL; j += 2) {
        {
            const float dr = r - palette[3 * j + 0];
            const float dg = g - palette[3 * j + 1];
            const float db = b - palette[3 * j + 2];
            best0 = fminf(best0, dr * dr + dg * dg + db * db);
        }
        {
            const float dr = r - palette[3 * j + 3];
            const float dg = g - palette[3 * j + 4];
            const float db = b - palette[3 * j + 5];
            best1 = fminf(best1, dr * dr + dg * dg + db * db);
        }
    }
    float v = __builtin_sqrtf(fminf(best0, best1));

    // Wave-64 shuffle reduction.
#pragma unroll
    for (int off = 32; off > 0; off >>= 1)
        v += __shfl_down(v, off, 64);

    __shared__ float wsum[BLOCK / 64];
    if ((tid & 63) == 0) wsum[tid >> 6] = v;
    __syncthreads();

    if (tid == 0) {
        const float s = wsum[0] + wsum[1] + wsum[2] + wsum[3];
        atomicAdd(out, s * (1.0f / (float)N_COLORS));
    }
}

extern "C" void kernel_launch(void* const* d_in, const int* in_sizes, int n_in,
                              void* d_out, int out_size, void* d_ws, size_t ws_size,
                              hipStream_t stream) {
    const float* colors  = (const float*)d_in[0];   // (131072, 3) fp32
    const float* palette = (const float*)d_in[1];   // (128, 3) fp32
    float* out = (float*)d_out;                     // 1 fp32 scalar

    // d_out is re-poisoned to 0xAA before every timed launch; zero the 4-byte
    // accumulator (graph-capture legal memset node).
    hipMemsetAsync(out, 0, sizeof(float), stream);

    const int grid = N_COLORS / BLOCK;  // 512 blocks = 2 blocks/CU
    nearest_color_loss_kernel<<<grid, BLOCK, 0, stream>>>(colors, palette, out);
}